// Round 1
// baseline (990.483 us; speedup 1.0000x reference)
//
#include <hip/hip_runtime.h>
#include <hip/hip_bf16.h>
#include <cstdint>

#define M_DIM 4096
#define K_DIM 4096
#define N_DIM 11008

typedef __attribute__((ext_vector_type(8))) short short8;
typedef __attribute__((ext_vector_type(4))) float floatx4;

__device__ __forceinline__ unsigned short f2bf(float f) {
    union { float f; unsigned u; } v; v.f = f;
    unsigned r = v.u + 0x7FFFu + ((v.u >> 16) & 1u);   // round-to-nearest-even
    return (unsigned short)(r >> 16);
}

__device__ __forceinline__ void async_copy16(const ushort* g, const ushort* l) {
    __builtin_amdgcn_global_load_lds(
        (const __attribute__((address_space(1))) void*)(uintptr_t)(const void*)g,
        (__attribute__((address_space(3))) void*)(uintptr_t)(const void*)l,
        16, 0, 0);
}

// Convert one row of x (fp32 -> bf16) and compute its row sum in fp32.
__global__ void prep_x_kernel(const float* __restrict__ x, ushort* __restrict__ xb,
                              float* __restrict__ s) {
    const int row = blockIdx.x;
    const int tid = threadIdx.x;                 // 256 threads
    const float*  xr = x  + (size_t)row * K_DIM;
    ushort*       xo = xb + (size_t)row * K_DIM;
    float sum = 0.f;
#pragma unroll
    for (int i = 0; i < 4; ++i) {
        int e = (tid + i * 256) * 4;             // element index, float4 granularity
        float4 v = *(const float4*)(xr + e);
        sum += v.x + v.y + v.z + v.w;
        ushort4 o = make_ushort4(f2bf(v.x), f2bf(v.y), f2bf(v.z), f2bf(v.w));
        *(ushort4*)(xo + e) = o;
    }
#pragma unroll
    for (int off = 32; off > 0; off >>= 1) sum += __shfl_down(sum, off, 64);
    __shared__ float red[4];
    if ((tid & 63) == 0) red[tid >> 6] = sum;
    __syncthreads();
    if (tid == 0) s[row] = red[0] + red[1] + red[2] + red[3];
}

// Convert int8-valued int32 weights -> bf16 (exact).
__global__ void prep_w_kernel(const int* __restrict__ w, ushort* __restrict__ wb, size_t n4) {
    size_t i = (size_t)blockIdx.x * blockDim.x + threadIdx.x;
    size_t stride = (size_t)gridDim.x * blockDim.x;
    for (; i < n4; i += stride) {
        int4 v = ((const int4*)w)[i];
        ushort4 o = make_ushort4(f2bf((float)v.x), f2bf((float)v.y),
                                 f2bf((float)v.z), f2bf((float)v.w));
        ((ushort4*)wb)[i] = o;
    }
}

// 128x128 tile bf16 GEMM, C = X * W^T, epilogue y = scale*(acc + off*s[m]) + bias
__global__ __launch_bounds__(256) void gemm_kernel(
        const ushort* __restrict__ xb, const ushort* __restrict__ wb,
        const float* __restrict__ s, const float* __restrict__ scale,
        const float* __restrict__ offset, const float* __restrict__ bias,
        float* __restrict__ y) {
    __shared__ ushort As[128 * 32];
    __shared__ ushort Bs[128 * 32];

    const int tid    = threadIdx.x;
    const int lane   = tid & 63;
    const int wave   = tid >> 6;
    const int wm     = wave >> 1;       // 2x2 wave grid over 128x128
    const int wn     = wave & 1;
    const int lane15 = lane & 15;
    const int quad   = lane >> 4;
    const int m0     = blockIdx.y * 128;
    const int n0     = blockIdx.x * 128;

    // Staging: each wave fills 2 contiguous 1KiB chunks of A and of B.
    // Chunk c covers rows c*16..c*16+15 (row stride 32 bf16 = 64B, no pad).
    const int chunk = wave * 2;
    const int rowIn = lane >> 2;            // 0..15 within chunk
    const int kofs  = (lane & 3) * 8;       // bf16 elements

    const ushort* aG0 = xb + (size_t)(m0 + chunk * 16 + rowIn) * K_DIM + kofs;
    const ushort* aG1 = aG0 + (size_t)16 * K_DIM;
    const ushort* bG0 = wb + (size_t)(n0 + chunk * 16 + rowIn) * K_DIM + kofs;
    const ushort* bG1 = bG0 + (size_t)16 * K_DIM;
    const ushort* aL0 = &As[chunk * 512];          // wave-uniform LDS bases
    const ushort* aL1 = &As[chunk * 512 + 512];
    const ushort* bL0 = &Bs[chunk * 512];
    const ushort* bL1 = &Bs[chunk * 512 + 512];

    floatx4 acc[4][4] = {};

    for (int kt = 0; kt < K_DIM; kt += 32) {
        __syncthreads();                   // previous compute done reading LDS
        async_copy16(aG0 + kt, aL0);
        async_copy16(aG1 + kt, aL1);
        async_copy16(bG0 + kt, bL0);
        async_copy16(bG1 + kt, bL1);
        __syncthreads();                   // drains vmcnt -> tiles visible

        short8 a[4], b[4];
#pragma unroll
        for (int i = 0; i < 4; ++i)
            a[i] = *(const short8*)&As[(wm * 64 + i * 16 + lane15) * 32 + quad * 8];
#pragma unroll
        for (int i = 0; i < 4; ++i)
            b[i] = *(const short8*)&Bs[(wn * 64 + i * 16 + lane15) * 32 + quad * 8];
#pragma unroll
        for (int i = 0; i < 4; ++i)
#pragma unroll
            for (int j = 0; j < 4; ++j)
                acc[i][j] = __builtin_amdgcn_mfma_f32_16x16x32_bf16(a[i], b[j], acc[i][j], 0, 0, 0);
    }

    // Row sums for the 16 distinct m values this lane touches.
    float srow[16];
#pragma unroll
    for (int i = 0; i < 4; ++i)
#pragma unroll
        for (int r = 0; r < 4; ++r)
            srow[i * 4 + r] = s[m0 + wm * 64 + i * 16 + quad * 4 + r];

#pragma unroll
    for (int j = 0; j < 4; ++j) {
        const int n = n0 + wn * 64 + j * 16 + lane15;
        const float sc = scale[n], of = offset[n], bi = bias[n];
#pragma unroll
        for (int i = 0; i < 4; ++i) {
            const int mb = m0 + wm * 64 + i * 16 + quad * 4;
#pragma unroll
            for (int r = 0; r < 4; ++r) {
                y[(size_t)(mb + r) * N_DIM + n] =
                    sc * (acc[i][j][r] + of * srow[i * 4 + r]) + bi;
            }
        }
    }
}

extern "C" void kernel_launch(void* const* d_in, const int* in_sizes, int n_in,
                              void* d_out, int out_size, void* d_ws, size_t ws_size,
                              hipStream_t stream) {
    const float* x      = (const float*)d_in[0];
    const int*   weight = (const int*)d_in[1];
    const float* scale  = (const float*)d_in[2];
    const float* offset = (const float*)d_in[3];
    const float* bias   = (const float*)d_in[4];
    float*       y      = (float*)d_out;

    // Workspace layout (bytes): xb bf16 M*K | wb bf16 N*K | s fp32 M
    ushort* xb = (ushort*)d_ws;
    ushort* wb = (ushort*)((char*)d_ws + (size_t)M_DIM * K_DIM * 2);
    float*  s  = (float*)((char*)d_ws + (size_t)M_DIM * K_DIM * 2 + (size_t)N_DIM * K_DIM * 2);

    prep_x_kernel<<<M_DIM, 256, 0, stream>>>(x, xb, s);
    size_t n4 = ((size_t)N_DIM * K_DIM) / 4;
    prep_w_kernel<<<8192, 256, 0, stream>>>(weight, wb, n4);

    dim3 grid(N_DIM / 128, M_DIM / 128);   // 86 x 32
    gemm_kernel<<<grid, 256, 0, stream>>>(xb, wb, s, scale, offset, bias, y);
}

// Round 2
// 908.257 us; speedup vs baseline: 1.0905x; 1.0905x over previous
//
#include <hip/hip_runtime.h>
#include <hip/hip_bf16.h>
#include <cstdint>

#define M_DIM 4096
#define K_DIM 4096
#define N_DIM 11008

typedef __attribute__((ext_vector_type(8))) short short8;
typedef __attribute__((ext_vector_type(4))) float floatx4;

__device__ __forceinline__ unsigned short f2bf(float f) {
    union { float f; unsigned u; } v; v.f = f;
    unsigned r = v.u + 0x7FFFu + ((v.u >> 16) & 1u);   // round-to-nearest-even
    return (unsigned short)(r >> 16);
}

__device__ __forceinline__ void async_copy16(const ushort* g, const ushort* l) {
    __builtin_amdgcn_global_load_lds(
        (const __attribute__((address_space(1))) void*)(uintptr_t)(const void*)g,
        (__attribute__((address_space(3))) void*)(uintptr_t)(const void*)l,
        16, 0, 0);
}

// Convert one row of x (fp32 -> bf16) and compute its row sum in fp32.
__global__ void prep_x_kernel(const float* __restrict__ x, ushort* __restrict__ xb,
                              float* __restrict__ s) {
    const int row = blockIdx.x;
    const int tid = threadIdx.x;                 // 256 threads
    const float*  xr = x  + (size_t)row * K_DIM;
    ushort*       xo = xb + (size_t)row * K_DIM;
    float sum = 0.f;
#pragma unroll
    for (int i = 0; i < 2; ++i) {
        int e = (tid + i * 256) * 8;             // 8 floats per unit
        float4 v0 = *(const float4*)(xr + e);
        float4 v1 = *(const float4*)(xr + e + 4);
        sum += v0.x + v0.y + v0.z + v0.w + v1.x + v1.y + v1.z + v1.w;
        short8 o;
        o[0] = f2bf(v0.x); o[1] = f2bf(v0.y); o[2] = f2bf(v0.z); o[3] = f2bf(v0.w);
        o[4] = f2bf(v1.x); o[5] = f2bf(v1.y); o[6] = f2bf(v1.z); o[7] = f2bf(v1.w);
        *(short8*)(xo + e) = o;
    }
#pragma unroll
    for (int off = 32; off > 0; off >>= 1) sum += __shfl_down(sum, off, 64);
    __shared__ float red[4];
    if ((tid & 63) == 0) red[tid >> 6] = sum;
    __syncthreads();
    if (tid == 0) s[row] = red[0] + red[1] + red[2] + red[3];
}

// Convert int8-valued int32 weights -> bf16 (exact). One ushort8 (16B) per thread.
__global__ void prep_w_kernel(const int* __restrict__ w, ushort* __restrict__ wb) {
    size_t i = (size_t)blockIdx.x * blockDim.x + threadIdx.x;
    const int4* wi = (const int4*)w;
    int4 v0 = wi[2 * i];
    int4 v1 = wi[2 * i + 1];
    short8 o;
    o[0] = f2bf((float)v0.x); o[1] = f2bf((float)v0.y);
    o[2] = f2bf((float)v0.z); o[3] = f2bf((float)v0.w);
    o[4] = f2bf((float)v1.x); o[5] = f2bf((float)v1.y);
    o[6] = f2bf((float)v1.z); o[7] = f2bf((float)v1.w);
    ((short8*)wb)[i] = o;
}

// 128x128 tile bf16 GEMM, C = X * W^T, epilogue y = scale*(acc + off*s[m]) + bias
__global__ __launch_bounds__(256) void gemm_kernel(
        const ushort* __restrict__ xb, const ushort* __restrict__ wb,
        const float* __restrict__ s, const float* __restrict__ scale,
        const float* __restrict__ offset, const float* __restrict__ bias,
        float* __restrict__ y) {
    __shared__ ushort As[128 * 32];
    __shared__ ushort Bs[128 * 32];

    const int tid    = threadIdx.x;
    const int lane   = tid & 63;
    const int wave   = tid >> 6;
    const int wm     = wave >> 1;       // 2x2 wave grid over 128x128
    const int wn     = wave & 1;
    const int lane15 = lane & 15;
    const int quad   = lane >> 4;

    // ---- Panel block swizzle: 256-block panels = 8 n-tiles x 32 m-tiles ----
    // Keeps concurrent working set (8MiB B-panel + 32MiB A) L3-resident.
    const int lin = blockIdx.y * gridDim.x + blockIdx.x;
    int m_tile, n_tile;
    {
        const int NT_FULL = (N_DIM / 128 / 8) * 8;        // 80
        const int FULL_BLOCKS = NT_FULL * (M_DIM / 128);  // 2560
        if (lin < FULL_BLOCKS) {
            int p = lin >> 8;          // panel id
            int q = lin & 255;
            n_tile = p * 8 + (q & 7);
            m_tile = q >> 3;
        } else {
            int l2 = lin - FULL_BLOCKS;                   // 0..191, 6 n-tiles left
            n_tile = NT_FULL + (l2 % 6);
            m_tile = l2 / 6;
        }
    }
    const int m0 = m_tile * 128;
    const int n0 = n_tile * 128;

    // ---- Staging with XOR k-chunk swizzle (kills LDS read bank conflicts) ----
    // Physical LDS slot for lane i is fixed (base + i*16B). We permute WHICH
    // logical k-chunk each lane fetches: c_log = c_phys ^ ((rowIn>>1)&3).
    const int chunk = wave * 2;
    const int rowIn = lane >> 2;                       // 0..15 within chunk
    const int clog  = (lane & 3) ^ ((rowIn >> 1) & 3);
    const int kofs  = clog * 8;                        // bf16 elements

    const ushort* aG0 = xb + (size_t)(m0 + chunk * 16 + rowIn) * K_DIM + kofs;
    const ushort* aG1 = aG0 + (size_t)16 * K_DIM;
    const ushort* bG0 = wb + (size_t)(n0 + chunk * 16 + rowIn) * K_DIM + kofs;
    const ushort* bG1 = bG0 + (size_t)16 * K_DIM;
    const ushort* aL0 = &As[chunk * 512];              // wave-uniform LDS bases
    const ushort* aL1 = &As[chunk * 512 + 512];
    const ushort* bL0 = &Bs[chunk * 512];
    const ushort* bL1 = &Bs[chunk * 512 + 512];

    floatx4 acc[4][4] = {};

    const int swz = (lane15 >> 1) & 3;                 // read-side unswizzle

    for (int kt = 0; kt < K_DIM; kt += 32) {
        __syncthreads();                   // previous compute done reading LDS
        async_copy16(aG0 + kt, aL0);
        async_copy16(aG1 + kt, aL1);
        async_copy16(bG0 + kt, bL0);
        async_copy16(bG1 + kt, bL1);
        __syncthreads();                   // drains vmcnt -> tiles visible

        short8 a[4], b[4];
#pragma unroll
        for (int i = 0; i < 4; ++i)
            a[i] = *(const short8*)&As[(wm * 64 + i * 16 + lane15) * 32 + (quad ^ swz) * 8];
#pragma unroll
        for (int i = 0; i < 4; ++i)
            b[i] = *(const short8*)&Bs[(wn * 64 + i * 16 + lane15) * 32 + (quad ^ swz) * 8];
#pragma unroll
        for (int i = 0; i < 4; ++i)
#pragma unroll
            for (int j = 0; j < 4; ++j)
                acc[i][j] = __builtin_amdgcn_mfma_f32_16x16x32_bf16(a[i], b[j], acc[i][j], 0, 0, 0);
    }

    // Row sums for the 16 distinct m values this lane touches.
    float srow[16];
#pragma unroll
    for (int i = 0; i < 4; ++i)
#pragma unroll
        for (int r = 0; r < 4; ++r)
            srow[i * 4 + r] = s[m0 + wm * 64 + i * 16 + quad * 4 + r];

#pragma unroll
    for (int j = 0; j < 4; ++j) {
        const int n = n0 + wn * 64 + j * 16 + lane15;
        const float sc = scale[n], of = offset[n], bi = bias[n];
#pragma unroll
        for (int i = 0; i < 4; ++i) {
            const int mb = m0 + wm * 64 + i * 16 + quad * 4;
#pragma unroll
            for (int r = 0; r < 4; ++r) {
                y[(size_t)(mb + r) * N_DIM + n] =
                    sc * (acc[i][j][r] + of * srow[i * 4 + r]) + bi;
            }
        }
    }
}

extern "C" void kernel_launch(void* const* d_in, const int* in_sizes, int n_in,
                              void* d_out, int out_size, void* d_ws, size_t ws_size,
                              hipStream_t stream) {
    const float* x      = (const float*)d_in[0];
    const int*   weight = (const int*)d_in[1];
    const float* scale  = (const float*)d_in[2];
    const float* offset = (const float*)d_in[3];
    const float* bias   = (const float*)d_in[4];
    float*       y      = (float*)d_out;

    // Workspace layout (bytes): xb bf16 M*K | wb bf16 N*K | s fp32 M
    ushort* xb = (ushort*)d_ws;
    ushort* wb = (ushort*)((char*)d_ws + (size_t)M_DIM * K_DIM * 2);
    float*  s  = (float*)((char*)d_ws + (size_t)M_DIM * K_DIM * 2 + (size_t)N_DIM * K_DIM * 2);

    prep_x_kernel<<<M_DIM, 256, 0, stream>>>(x, xb, s);
    int wblocks = (int)(((size_t)N_DIM * K_DIM / 8) / 256);   // 22016
    prep_w_kernel<<<wblocks, 256, 0, stream>>>(weight, wb);

    dim3 grid(N_DIM / 128, M_DIM / 128);   // 86 x 32
    gemm_kernel<<<grid, 256, 0, stream>>>(xb, wb, s, scale, offset, bias, y);
}